// Round 15
// baseline (104.066 us; speedup 1.0000x reference)
//
#include <hip/hip_runtime.h>
#include <hip/hip_bf16.h>

typedef __attribute__((ext_vector_type(8))) short bf16x8;
typedef __attribute__((ext_vector_type(4))) float f32x4;
typedef unsigned short u16;

// Problem constants
constexpr int NR      = 4096;
constexpr int INF     = 1024;
constexpr int HEAD_N  = 2002;
constexpr int HEAD_NP = 2048;     // 16 col-tiles of 128
constexpr int C0_LO   = 2000, C0_HI = 10000;
constexpr int C0_N    = 8000;
constexpr int C1_N    = 40257;
constexpr int C1_NP   = 40320;
constexpr int K0      = 256;
constexpr int K1      = 64;
constexpr int PCAT    = 320;      // 256 + 64 concatenated proj rows
constexpr int IGNORE  = -1;
constexpr float LOG2E = 1.4426950408889634f;
constexpr float LN2   = 0.6931471805599453f;

// geometry
constexpr int S0      = 50;       // C0 splits: tps=5 over 250 tiles (CT=32, 128-row blocks)
constexpr int TPS0    = 5;
constexpr int S1      = 64;       // C1 splits: tps=5 over 315 tiles (CT=128, 256-row blocks)
constexpr int TPS1    = 5;        //   64%8==0 -> per-XCD split affinity preserved
constexpr int NHP     = 32;       // head partial slots: 16 col-tiles x 2 wc halves
constexpr int HEADB   = 512;      // 16 ct x 32 rb  (ct = bid>>5, rb = bid&31)
constexpr int C1SLOTS = 768;      // grid-stride slots (stride%8==0 keeps affinity)
constexpr int C0SLOTS = 256;
constexpr int MEGA_GRID = HEADB + C1SLOTS + C0SLOTS;  // 1536
constexpr int NPROJB  = 96;       // proj blocks inside cvt kernel: 32 rb x 3 ct
constexpr int CVT_GRID = 2048;

static __device__ __forceinline__ u16 f32_to_bf16(float f) {
    unsigned int u = __float_as_uint(f);
    return (u16)((u + 0x7FFFu + ((u >> 16) & 1u)) >> 16);
}
static __device__ __forceinline__ float bf2f(u16 v) {
    unsigned int u = ((unsigned int)v) << 16;
    return __uint_as_float(u);
}
static __device__ __forceinline__ bf16x8 cvt8(float4 a, float4 b, float sc) {
    bf16x8 o;
    o[0] = (short)f32_to_bf16(a.x * sc); o[1] = (short)f32_to_bf16(a.y * sc);
    o[2] = (short)f32_to_bf16(a.z * sc); o[3] = (short)f32_to_bf16(a.w * sc);
    o[4] = (short)f32_to_bf16(b.x * sc); o[5] = (short)f32_to_bf16(b.y * sc);
    o[6] = (short)f32_to_bf16(b.z * sc); o[7] = (short)f32_to_bf16(b.w * sc);
    return o;
}

static __device__ __forceinline__ float fast_exp2(float x) {
#if __has_builtin(__builtin_amdgcn_exp2f)
    return __builtin_amdgcn_exp2f(x);
#else
    return __expf(x * LN2);
#endif
}

static __device__ __forceinline__ void gload_lds16(const u16* g, u16* l) {
    __builtin_amdgcn_global_load_lds(
        (const __attribute__((address_space(1))) unsigned int*)g,
        (__attribute__((address_space(3))) unsigned int*)l, 16, 0, 0);
}

// ---------------- fused: proj GEMM (96 blocks) + compaction + f32->bf16 convert ----------------
// proj blocks: LDS-staged 128x128 tile GEMM reading f32 x/proj directly,
// converting to bf16 in-register before ds_write (same RNE as the convert path
// -> hcatb is bit-identical to the old two-step path). r9's failure was the
// NO-LDS register-chain version; this keeps the proven tile structure.
struct CvtSegs { const float* s[4]; u16* d[4]; int n8[4]; float sc[4]; };

__launch_bounds__(256, 4)
__global__ void cvt_compact(CvtSegs segs,
                            const float* __restrict__ x,
                            const float* __restrict__ proj0, const float* __restrict__ proj1,
                            u16* __restrict__ hcatb,
                            const int* __restrict__ tgt,
                            int* __restrict__ c0list, int* __restrict__ c1list,
                            int* __restrict__ crow, int* __restrict__ cnts) {
    __shared__ u16 plds[2][8192];     // 32 KB: A,B bf16 tiles for proj blocks
    const int bid = blockIdx.x;
    const int tid = threadIdx.x;
    const int wid = tid >> 6, lane = tid & 63;

    if (bid < NPROJB) {
        const int rb = bid & 31, ct = bid >> 5;      // ct 0..2
        const int row0 = rb * 128, col0 = ct * 128;
        const int wr = wid >> 1, wc = wid & 1;

        f32x4 acc[4][4];
#pragma unroll
        for (int m = 0; m < 4; ++m)
#pragma unroll
            for (int n = 0; n < 4; ++n) acc[m][n] = (f32x4){0.f, 0.f, 0.f, 0.f};

        for (int ks = 0; ks < INF / 64; ++ks) {
            const int k0 = ks * 64;
            // stage: 1024 slots (128 rows x 8 slots of 8 elems), 4 slots/thread,
            // s = tid + j*256 -> consecutive lanes read consecutive 32B -> coalesced
#pragma unroll
            for (int j = 0; j < 4; ++j) {
                const int s = tid + j * 256;
                const int row = s >> 3, sl = s & 7;
                {
                    const float* ap = x + (size_t)(row0 + row) * INF + k0 + sl * 8;
                    ((bf16x8*)plds[0])[row * 8 + (sl ^ (row & 7))] =
                        cvt8(*(const float4*)ap, *(const float4*)(ap + 4), 1.0f);
                }
                {
                    const int p = col0 + row;
                    bf16x8 v = {};
                    if (p < PCAT) {
                        const float* bp = (p < 256 ? proj0 + (size_t)p * INF
                                                   : proj1 + (size_t)(p - 256) * INF) + k0 + sl * 8;
                        v = cvt8(*(const float4*)bp, *(const float4*)(bp + 4), 1.0f);
                    }
                    ((bf16x8*)plds[1])[row * 8 + (sl ^ (row & 7))] = v;
                }
            }
            __syncthreads();
            const bf16x8* A8 = (const bf16x8*)plds[0];
            const bf16x8* B8 = (const bf16x8*)plds[1];
            bf16x8 af[4][2], bfr[4][2];
#pragma unroll
            for (int m = 0; m < 4; ++m) {
                const int ar = wr * 64 + m * 16 + (lane & 15);
#pragma unroll
                for (int ks2 = 0; ks2 < 2; ++ks2)
                    af[m][ks2] = A8[ar * 8 + ((ks2 * 4 + (lane >> 4)) ^ (ar & 7))];
            }
#pragma unroll
            for (int n = 0; n < 4; ++n) {
                const int br = wc * 64 + n * 16 + (lane & 15);
#pragma unroll
                for (int ks2 = 0; ks2 < 2; ++ks2)
                    bfr[n][ks2] = B8[br * 8 + ((ks2 * 4 + (lane >> 4)) ^ (br & 7))];
            }
#pragma unroll
            for (int ks2 = 0; ks2 < 2; ++ks2)
#pragma unroll
                for (int m = 0; m < 4; ++m)
#pragma unroll
                    for (int n = 0; n < 4; ++n)
                        acc[m][n] = __builtin_amdgcn_mfma_f32_16x16x32_bf16(
                            af[m][ks2], bfr[n][ks2], acc[m][n], 0, 0, 0);
            __syncthreads();
        }
#pragma unroll
        for (int m = 0; m < 4; ++m)
#pragma unroll
            for (int n = 0; n < 4; ++n) {
                const int col = col0 + wc * 64 + n * 16 + (lane & 15);
                if (col < PCAT) {
#pragma unroll
                    for (int r = 0; r < 4; ++r) {
                        const int row = row0 + wr * 64 + m * 16 + (lane >> 4) * 4 + r;
                        hcatb[(size_t)row * PCAT + col] = f32_to_bf16(acc[m][n][r]);
                    }
                }
            }
        return;
    }

    if (bid == NPROJB) {
        // band compaction (slot order atomic-nondeterministic; downstream values
        // are slot-independent -> loss replay-identical)
        __shared__ int b0s, b1s;
        if (tid == 0) { b0s = 0; b1s = 0; }
        __syncthreads();
        for (int it = 0; it < NR / 256; ++it) {
            const int r = it * 256 + tid;
            const int t = tgt[r];
            const bool in0 = (t >= C0_LO) && (t < C0_HI);
            const bool in1 = (t >= C0_HI);
            unsigned long long m0 = __ballot(in0);
            unsigned long long m1 = __ballot(in1);
            int base0 = 0, base1 = 0;
            if (lane == 0) {
                base0 = atomicAdd(&b0s, (int)__popcll(m0));
                base1 = atomicAdd(&b1s, (int)__popcll(m1));
            }
            base0 = __shfl(base0, 0, 64);
            base1 = __shfl(base1, 0, 64);
            const unsigned long long lt = (1ULL << lane) - 1ULL;
            if (in0) { int s = base0 + (int)__popcll(m0 & lt); c0list[s] = r; crow[r] = s; }
            else if (in1) { int s = base1 + (int)__popcll(m1 & lt); c1list[s] = r; crow[r] = s; }
            else crow[r] = 0;
        }
        __syncthreads();
        const int c0 = b0s, c1 = b1s;
        const int p0 = (c0 + 127) & ~127;          // C0 blocks cover 128 rows
        const int p1 = (c1 + 255) & ~255;          // C1 blocks cover 256 rows
        if (tid == 0) { cnts[0] = c0; cnts[1] = c1; cnts[2] = p0; cnts[3] = p1; }
        for (int i = c0 + tid; i < p0; i += 256) c0list[i] = 0;
        for (int i = c1 + tid; i < p1; i += 256) c1list[i] = 0;
    }

    // convert segments: x, head_w(*log2e), out0(*log2e), out1(*log2e)
    const int stride = (CVT_GRID - NPROJB) * 256;
    const int gid = (bid - NPROJB) * 256 + tid;
#pragma unroll
    for (int seg = 0; seg < 4; ++seg) {
        const float4* sp = (const float4*)segs.s[seg];
        bf16x8* dp = (bf16x8*)segs.d[seg];
        const int n8 = segs.n8[seg];
        const float sc = segs.sc[seg];
        for (int i = gid; i < n8; i += stride)
            dp[i] = cvt8(sp[2 * i], sp[2 * i + 1], sc);
    }
}

// ---------------- mega kernel sections ----------------
// head section (tile 128x128, K=1024) — per-(col-tile, wc-half) partial store.
static __device__ void head_section(int rb, int ct,
                                    const u16* __restrict__ A, const u16* __restrict__ B,
                                    const int* __restrict__ tgt,
                                    float* __restrict__ SEHp, float* __restrict__ TL,
                                    u16* ldsA, u16* ldsB)
{
    constexpr int K = INF;
    const int tid = threadIdx.x, wid = tid >> 6, lane = tid & 63;
    const int wr = wid >> 1, wc = wid & 1;
    const int row0 = rb * 128, col0 = ct * 128;

    f32x4 acc[4][4];
#pragma unroll
    for (int m = 0; m < 4; ++m)
#pragma unroll
        for (int n = 0; n < 4; ++n) acc[m][n] = (f32x4){0.f, 0.f, 0.f, 0.f};

    const int srow = lane >> 3;
    const int ssw  = (lane & 7) ^ srow;

    for (int ks = 0; ks < K / 64; ++ks) {
        const int k0 = ks * 64;
#pragma unroll
        for (int q = 0; q < 4; ++q) {
            const int c = q * 4 + wid, row = c * 8 + srow;
            gload_lds16(A + (size_t)(row0 + row) * K + k0 + ssw * 8, ldsA + c * 512);
        }
#pragma unroll
        for (int q = 0; q < 4; ++q) {
            const int c = q * 4 + wid, row = c * 8 + srow;
            gload_lds16(B + (size_t)(col0 + row) * K + k0 + ssw * 8, ldsB + c * 512);
        }
        __syncthreads();
        const bf16x8* A8 = (const bf16x8*)ldsA;
        const bf16x8* B8 = (const bf16x8*)ldsB;
        bf16x8 af[4][2], bfr[4][2];
#pragma unroll
        for (int m = 0; m < 4; ++m) {
            const int ar = wr * 64 + m * 16 + (lane & 15);
#pragma unroll
            for (int ks2 = 0; ks2 < 2; ++ks2)
                af[m][ks2] = A8[ar * 8 + ((ks2 * 4 + (lane >> 4)) ^ (ar & 7))];
        }
#pragma unroll
        for (int n = 0; n < 4; ++n) {
            const int br = wc * 64 + n * 16 + (lane & 15);
#pragma unroll
            for (int ks2 = 0; ks2 < 2; ++ks2)
                bfr[n][ks2] = B8[br * 8 + ((ks2 * 4 + (lane >> 4)) ^ (br & 7))];
        }
#pragma unroll
        for (int ks2 = 0; ks2 < 2; ++ks2)
#pragma unroll
            for (int m = 0; m < 4; ++m)
#pragma unroll
                for (int n = 0; n < 4; ++n)
                    acc[m][n] = __builtin_amdgcn_mfma_f32_16x16x32_bf16(
                        af[m][ks2], bfr[n][ks2], acc[m][n], 0, 0, 0);
        __syncthreads();
    }

    const int slot = ct * 2 + wc;
#pragma unroll
    for (int m = 0; m < 4; ++m) {
        int th[4];
#pragma unroll
        for (int r = 0; r < 4; ++r) {
            const int t = tgt[row0 + wr * 64 + m * 16 + (lane >> 4) * 4 + r];
            th[r] = (t < 0) ? 0 : (t < C0_LO ? t : (t < C0_HI ? C0_LO : C0_LO + 1));
        }
        f32x4 rs = (f32x4){0.f, 0.f, 0.f, 0.f};
#pragma unroll
        for (int n = 0; n < 4; ++n) {
            const int cls = col0 + wc * 64 + n * 16 + (lane & 15);
            if (cls < HEAD_N) {
#pragma unroll
                for (int r = 0; r < 4; ++r) {
                    rs[r] += fast_exp2(acc[m][n][r]);
                    if (th[r] == cls) {
                        const int lrow = wr * 64 + m * 16 + (lane >> 4) * 4 + r;
                        TL[row0 + lrow] = acc[m][n][r];
                    }
                }
            }
        }
#pragma unroll
        for (int msk = 1; msk < 16; msk <<= 1)
#pragma unroll
            for (int r = 0; r < 4; ++r) rs[r] += __shfl_xor(rs[r], msk, 64);
        if ((lane & 15) == 0) {
            const int rbase = row0 + wr * 64 + m * 16 + (lane >> 4) * 4;
#pragma unroll
            for (int r = 0; r < 4; ++r) SEHp[(size_t)slot * NR + rbase + r] = rs[r];
        }
    }
}

// cluster section: compacted rows in registers, W streamed via double-buffered LDS
template<int K, int CT, int MSETS>
static __device__ void sumexp_section(const u16* __restrict__ Hbase, int ldh,
                                      const int* __restrict__ list,
                                      const u16* __restrict__ W,
                                      int nreal, int ntiles, int tps,
                                      int rb, int split, float* __restrict__ SEp,
                                      u16* lds)
{
    constexpr int NKF   = K / 32;
    constexpr int SLOTS = K / 8;
    constexpr int CHUNKS = CT * K * 2 / 4096;
    constexpr int RPC   = 256 / SLOTS;
    constexpr int NT    = CT / 16;
    constexpr int BROWS = MSETS * 64;       // rows per block

    const int tid = threadIdx.x, wid = tid >> 6, lane = tid & 63;
    const int row0 = rb * BROWS + wid * (MSETS * 16);

    const int t0 = split * tps;
    const int t1 = min(t0 + tps, ntiles);

    bf16x8 afr[MSETS][NKF];
#pragma unroll
    for (int m = 0; m < MSETS; ++m) {
        const int orow = list[row0 + m * 16 + (lane & 15)];
        const u16* hr = Hbase + (size_t)orow * ldh + (lane >> 4) * 8;
#pragma unroll
        for (int kf = 0; kf < NKF; ++kf)
            afr[m][kf] = *(const bf16x8*)(hr + kf * 32);
    }

    float rs[MSETS][4];
#pragma unroll
    for (int m = 0; m < MSETS; ++m)
#pragma unroll
        for (int r = 0; r < 4; ++r) rs[m][r] = 0.f;

    const int trow  = tid / SLOTS;
    const int swoff = ((tid % SLOTS) ^ (trow & 7)) * 8;

    auto STAGE = [&](int t, int buf) {
        const u16* wb = W + (size_t)t * CT * K + (size_t)trow * K + swoff;
        u16* lb = lds + buf * (CT * K) + wid * 512;
#pragma unroll
        for (int c = 0; c < CHUNKS; ++c)
            gload_lds16(wb + (size_t)c * RPC * K, lb + c * 2048);
    };

    int cur = 0;
    STAGE(t0, 0);
    __syncthreads();

    for (int t = t0; t < t1; ++t) {
        if (t + 1 < t1) STAGE(t + 1, cur ^ 1);
        const bf16x8* B8 = (const bf16x8*)(lds + cur * (CT * K));
        const bool full = (t + 1) * CT <= nreal;
#pragma unroll
        for (int n = 0; n < NT; ++n) {
            const int br = n * 16 + (lane & 15);
            bf16x8 bfr[NKF];
#pragma unroll
            for (int kf = 0; kf < NKF; ++kf)
                bfr[kf] = B8[br * SLOTS + ((kf * 4 + (lane >> 4)) ^ (br & 7))];
            f32x4 acc[MSETS];
#pragma unroll
            for (int m = 0; m < MSETS; ++m) acc[m] = (f32x4){0.f, 0.f, 0.f, 0.f};
#pragma unroll
            for (int m = 0; m < MSETS; ++m)
#pragma unroll
                for (int kf = 0; kf < NKF; ++kf)
                    acc[m] = __builtin_amdgcn_mfma_f32_16x16x32_bf16(
                        afr[m][kf], bfr[kf], acc[m], 0, 0, 0);
            if (full || (t * CT + n * 16 + (lane & 15)) < nreal) {
#pragma unroll
                for (int m = 0; m < MSETS; ++m)
#pragma unroll
                    for (int r = 0; r < 4; ++r) rs[m][r] += fast_exp2(acc[m][r]);
            }
        }
        __syncthreads();
        cur ^= 1;
    }

#pragma unroll
    for (int msk = 1; msk < 16; msk <<= 1)
#pragma unroll
        for (int m = 0; m < MSETS; ++m)
#pragma unroll
            for (int r = 0; r < 4; ++r) rs[m][r] += __shfl_xor(rs[m][r], msk, 64);
    if ((lane & 15) == 0) {
        const int rbase = row0 + (lane >> 4) * 4;
#pragma unroll
        for (int m = 0; m < MSETS; ++m)
#pragma unroll
            for (int r = 0; r < 4; ++r)
                SEp[(size_t)split * NR + rbase + m * 16 + r] = rs[m][r];
    }
}

// Type-sequential layout + ghost-free grid-stride. LDS = 32 KB exactly.
__launch_bounds__(256, 4)
__global__ void mega_kernel(const u16* __restrict__ xb, const u16* __restrict__ whb,
                            const u16* __restrict__ hcatb,
                            const u16* __restrict__ o0b, const u16* __restrict__ o1b,
                            const int* __restrict__ tgt,
                            const int* __restrict__ c0list, const int* __restrict__ c1list,
                            const int* __restrict__ cnts,
                            float* __restrict__ SEHp, float* __restrict__ TL,
                            float* __restrict__ C0p, float* __restrict__ C1p)
{
    __shared__ u16 smem[2][8192];
    const int bid = blockIdx.x;

    if (bid < HEADB) {
        head_section(bid & 31, bid >> 5, xb, whb, tgt, SEHp, TL,
                     smem[0], smem[1]);
    } else if (bid < HEADB + C1SLOTS) {
        const int c = bid - HEADB;
        const int W1 = (cnts[3] >> 8) * S1;     // live 256-row groups * splits
        for (int w = c; w < W1; w += C1SLOTS)
            sumexp_section<K1, 128, 4>(hcatb + 256, PCAT, c1list, o1b,
                                       C1_N, C1_NP / 128, TPS1, w / S1, w % S1, C1p, smem[0]);
    } else {
        const int c = bid - (HEADB + C1SLOTS);
        const int W0 = (cnts[2] >> 7) * S0;     // live 128-row groups * splits
        for (int w = c; w < W0; w += C0SLOTS)
            sumexp_section<K0, 32, 2>(hcatb, PCAT, c0list, o0b,
                                      C0_N, C0_N / 32, TPS0, w / S0, w % S0, C0p, smem[0]);
    }
}

// ---------------- per-row epilogue: one wave per row (contention-free stores) ----------------
__global__ void epilogue_kernel(const int* __restrict__ tgt, const float* __restrict__ tl,
                                const float* __restrict__ out0, const float* __restrict__ out1,
                                const u16* __restrict__ hcatb,
                                const float* __restrict__ SEHp, const float* __restrict__ C0p,
                                const float* __restrict__ C1p, const int* __restrict__ crow,
                                float* __restrict__ rowlogp, float* __restrict__ rowvalid) {
    const int wid = threadIdx.x >> 6, lane = threadIdx.x & 63;
    const int r = blockIdx.x * 4 + wid;
    const int t = tgt[r];
    const bool valid = (t != IGNORE);
    const int tc = valid ? t : 0;
    const int band = (tc < C0_LO) ? 0 : (tc < C0_HI) ? 1 : 2;
    const int cr = crow[r];

    float p2 = 0.f;
    if (band == 1) {
        const u16* hr = hcatb + (size_t)r * PCAT;
        const float* crp = out0 + (size_t)(tc - C0_LO) * K0;
        for (int k = lane; k < K0; k += 64) p2 += bf2f(hr[k]) * crp[k];
    } else if (band == 2) {
        p2 = bf2f(hcatb[(size_t)r * PCAT + 256 + lane]) * out1[(size_t)(tc - C0_HI) * K1 + lane];
    }
#pragma unroll
    for (int msk = 32; msk >= 1; msk >>= 1) p2 += __shfl_xor(p2, msk, 64);

    float hp = (lane < NHP) ? SEHp[(size_t)lane * NR + r] : 0.f;
    float cp = 0.f;
    if (band == 1 && lane < S0) cp = C0p[(size_t)lane * NR + cr];
    if (band == 2 && lane < S1) cp = C1p[(size_t)lane * NR + cr];
#pragma unroll
    for (int msk = 1; msk < 64; msk <<= 1) {
        hp += __shfl_xor(hp, msk, 64);
        cp += __shfl_xor(cp, msk, 64);
    }

    if (lane == 0) {
        float logp = LN2 * tl[r] - __logf(hp);
        if (band != 0) logp += p2 - __logf(cp);
        rowlogp[r]  = valid ? logp : 0.f;
        rowvalid[r] = valid ? 1.f : 0.f;
    }
}

// ---------------- deterministic final reduce ----------------
__global__ void final_reduce(const float* __restrict__ rowlogp,
                             const float* __restrict__ rowvalid, float* __restrict__ out) {
    __shared__ float sl[256], sv[256];
    const int tid = threadIdx.x;
    float a = 0.f, b = 0.f;
    for (int i = tid; i < NR; i += 256) { a += rowlogp[i]; b += rowvalid[i]; }
    sl[tid] = a; sv[tid] = b;
    __syncthreads();
    for (int s = 128; s > 0; s >>= 1) {
        if (tid < s) { sl[tid] += sl[tid + s]; sv[tid] += sv[tid + s]; }
        __syncthreads();
    }
    if (tid == 0) out[0] = -sl[0] / sv[0];
}

extern "C" void kernel_launch(void* const* d_in, const int* in_sizes, int n_in,
                              void* d_out, int out_size, void* d_ws, size_t ws_size,
                              hipStream_t stream) {
    const float* x      = (const float*)d_in[0];
    const int*   tgt    = (const int*)d_in[1];
    const float* head_w = (const float*)d_in[2];
    const float* proj0  = (const float*)d_in[3];
    const float* out0   = (const float*)d_in[4];
    const float* proj1  = (const float*)d_in[5];
    const float* out1   = (const float*)d_in[6];
    float* loss = (float*)d_out;

    char* base = (char*)d_ws;
    size_t off = 0;
    auto alloc = [&](size_t bytes) { char* p = base + off; off += (bytes + 255) & ~(size_t)255; return p; };

    u16* xb    = (u16*)alloc((size_t)NR * INF * 2);
    u16* whb   = (u16*)alloc((size_t)HEAD_NP * INF * 2);
    u16* o0b   = (u16*)alloc((size_t)C0_N * K0 * 2);
    u16* o1b   = (u16*)alloc((size_t)C1_NP * K1 * 2);
    u16* hcatb = (u16*)alloc((size_t)NR * PCAT * 2);
    float* SEHp = (float*)alloc((size_t)NHP * NR * 4);
    float* C0p  = (float*)alloc((size_t)S0 * NR * 4);
    float* C1p  = (float*)alloc((size_t)S1 * NR * 4);
    float* tl   = (float*)alloc((size_t)NR * 4);
    int* c0list = (int*)alloc((size_t)(NR + 256) * 4);
    int* c1list = (int*)alloc((size_t)(NR + 256) * 4);
    int* crow   = (int*)alloc((size_t)NR * 4);
    int* cnts   = (int*)alloc(4 * 4);
    float* rowlogp  = (float*)alloc((size_t)NR * 4);
    float* rowvalid = (float*)alloc((size_t)NR * 4);

    CvtSegs segs;
    segs.s[0] = x;      segs.d[0] = xb;   segs.n8[0] = NR * INF / 8;      segs.sc[0] = 1.0f;
    segs.s[1] = head_w; segs.d[1] = whb;  segs.n8[1] = HEAD_N * INF / 8;  segs.sc[1] = LOG2E;
    segs.s[2] = out0;   segs.d[2] = o0b;  segs.n8[2] = C0_N * K0 / 8;     segs.sc[2] = LOG2E;
    segs.s[3] = out1;   segs.d[3] = o1b;  segs.n8[3] = C1_N * K1 / 8;     segs.sc[3] = LOG2E;
    // proj GEMM (96 blocks, f32-direct) + compaction + converts, one dispatch
    cvt_compact<<<CVT_GRID, 256, 0, stream>>>(segs, x, proj0, proj1, hcatb,
                                              tgt, c0list, c1list, crow, cnts);

    // head GEMM+sumexp, then C1 (256-row blocks), then C0 (type-sequential, ghost-free)
    mega_kernel<<<MEGA_GRID, 256, 0, stream>>>(xb, whb, hcatb, o0b, o1b, tgt,
                                               c0list, c1list, cnts, SEHp, tl, C0p, C1p);

    epilogue_kernel<<<NR / 4, 256, 0, stream>>>(tgt, tl, out0, out1, hcatb,
                                                SEHp, C0p, C1p, crow, rowlogp, rowvalid);
    final_reduce<<<1, 256, 0, stream>>>(rowlogp, rowvalid, loss);
    (void)in_sizes; (void)n_in; (void)out_size; (void)ws_size;
}

// Round 16
// 88.443 us; speedup vs baseline: 1.1766x; 1.1766x over previous
//
#include <hip/hip_runtime.h>
#include <hip/hip_bf16.h>

typedef __attribute__((ext_vector_type(8))) short bf16x8;
typedef __attribute__((ext_vector_type(4))) float f32x4;
typedef unsigned short u16;

// Problem constants
constexpr int NR      = 4096;
constexpr int INF     = 1024;
constexpr int HEAD_N  = 2002;
constexpr int HEAD_NP = 2048;     // 16 col-tiles of 128
constexpr int C0_LO   = 2000, C0_HI = 10000;
constexpr int C0_N    = 8000;
constexpr int C1_N    = 40257;
constexpr int C1_NP   = 40320;
constexpr int K0      = 256;
constexpr int K1      = 64;
constexpr int PCAT    = 320;      // 256 + 64 concatenated proj rows
constexpr int PCAT_P  = 384;      // 3 col-tiles of 128
constexpr int WCAT_R  = HEAD_NP + PCAT_P;  // 2432 rows in merged B
constexpr int IGNORE  = -1;
constexpr float LOG2E = 1.4426950408889634f;
constexpr float LN2   = 0.6931471805599453f;

// geometry
constexpr int S0      = 50;       // C0 splits: tps=5 over 250 tiles (CT=32, 128-row blocks)
constexpr int TPS0    = 5;
constexpr int S1      = 64;       // C1 splits: tps=5 over 315 tiles (CT=128, 256-row blocks)
constexpr int TPS1    = 5;        //   64%8==0 -> per-XCD split affinity preserved
constexpr int NHP     = 32;       // head partial slots: 16 col-tiles x 2 wc halves
constexpr int HEADB   = 512;      // 16 ct x 32 rb  (ct = bid>>5, rb = bid&31)
constexpr int C1SLOTS = 768;      // grid-stride slots (stride%8==0 keeps affinity)
constexpr int C0SLOTS = 256;
constexpr int MEGA_GRID = HEADB + C1SLOTS + C0SLOTS;  // 1536

static __device__ __forceinline__ u16 f32_to_bf16(float f) {
    unsigned int u = __float_as_uint(f);
    return (u16)((u + 0x7FFFu + ((u >> 16) & 1u)) >> 16);
}
static __device__ __forceinline__ float bf2f(u16 v) {
    unsigned int u = ((unsigned int)v) << 16;
    return __uint_as_float(u);
}

static __device__ __forceinline__ float fast_exp2(float x) {
#if __has_builtin(__builtin_amdgcn_exp2f)
    return __builtin_amdgcn_exp2f(x);
#else
    return __expf(x * LN2);
#endif
}

static __device__ __forceinline__ void gload_lds16(const u16* g, u16* l) {
    __builtin_amdgcn_global_load_lds(
        (const __attribute__((address_space(1))) unsigned int*)g,
        (__attribute__((address_space(3))) unsigned int*)l, 16, 0, 0);
}

// ---------------- fused: band compaction (block 0) + multi-segment f32->bf16 ----------------
struct CvtSegs { const float* s[6]; u16* d[6]; int n8[6]; float sc[6]; };

__global__ void cvt_compact(CvtSegs segs, const int* __restrict__ tgt,
                            int* __restrict__ c0list, int* __restrict__ c1list,
                            int* __restrict__ crow, int* __restrict__ cnts) {
    if (blockIdx.x == 0) {
        __shared__ int b0s, b1s;
        const int tid = threadIdx.x;
        const int lane = tid & 63;
        if (tid == 0) { b0s = 0; b1s = 0; }
        __syncthreads();
        for (int it = 0; it < NR / 256; ++it) {
            const int r = it * 256 + tid;
            const int t = tgt[r];
            const bool in0 = (t >= C0_LO) && (t < C0_HI);
            const bool in1 = (t >= C0_HI);
            unsigned long long m0 = __ballot(in0);
            unsigned long long m1 = __ballot(in1);
            int base0 = 0, base1 = 0;
            if (lane == 0) {
                base0 = atomicAdd(&b0s, (int)__popcll(m0));
                base1 = atomicAdd(&b1s, (int)__popcll(m1));
            }
            base0 = __shfl(base0, 0, 64);
            base1 = __shfl(base1, 0, 64);
            const unsigned long long lt = (1ULL << lane) - 1ULL;
            if (in0) { int s = base0 + (int)__popcll(m0 & lt); c0list[s] = r; crow[r] = s; }
            else if (in1) { int s = base1 + (int)__popcll(m1 & lt); c1list[s] = r; crow[r] = s; }
            else crow[r] = 0;
        }
        __syncthreads();
        const int c0 = b0s, c1 = b1s;
        const int p0 = (c0 + 127) & ~127;          // C0 blocks cover 128 rows
        const int p1 = (c1 + 255) & ~255;          // C1 blocks cover 256 rows
        if (threadIdx.x == 0) { cnts[0] = c0; cnts[1] = c1; cnts[2] = p0; cnts[3] = p1; }
        for (int i = c0 + (int)threadIdx.x; i < p0; i += 256) c0list[i] = 0;
        for (int i = c1 + (int)threadIdx.x; i < p1; i += 256) c1list[i] = 0;
    }

    const int stride = gridDim.x * blockDim.x;
    const int gid = blockIdx.x * blockDim.x + threadIdx.x;
#pragma unroll
    for (int seg = 0; seg < 6; ++seg) {
        const float4* sp = (const float4*)segs.s[seg];
        bf16x8* dp = (bf16x8*)segs.d[seg];
        const int n8 = segs.n8[seg];
        const float sc = segs.sc[seg];
        for (int i = gid; i < n8; i += stride) {
            float4 a = sp[2 * i], b = sp[2 * i + 1];
            bf16x8 o;
            o[0] = (short)f32_to_bf16(a.x * sc); o[1] = (short)f32_to_bf16(a.y * sc);
            o[2] = (short)f32_to_bf16(a.z * sc); o[3] = (short)f32_to_bf16(a.w * sc);
            o[4] = (short)f32_to_bf16(b.x * sc); o[5] = (short)f32_to_bf16(b.y * sc);
            o[6] = (short)f32_to_bf16(b.z * sc); o[7] = (short)f32_to_bf16(b.w * sc);
            dp[i] = o;
        }
    }
}

// ---------------- proj GEMM: hcat(bf16) = X @ [proj0;proj1]^T (LDS-staged) ----------------
__launch_bounds__(256, 2)
__global__ void proj_tile(const u16* __restrict__ A, const u16* __restrict__ B,
                          u16* __restrict__ HB)
{
    constexpr int K = INF;
    __shared__ u16 ldsA[128 * 64];
    __shared__ u16 ldsB[128 * 64];
    const int tid = threadIdx.x, wid = tid >> 6, lane = tid & 63;
    const int wr = wid >> 1, wc = wid & 1;
    const int row0 = blockIdx.x * 128, col0 = blockIdx.y * 128;

    f32x4 acc[4][4];
#pragma unroll
    for (int m = 0; m < 4; ++m)
#pragma unroll
        for (int n = 0; n < 4; ++n) acc[m][n] = (f32x4){0.f, 0.f, 0.f, 0.f};

    const int srow = lane >> 3;
    const int ssw  = (lane & 7) ^ srow;

    for (int ks = 0; ks < K / 64; ++ks) {
        const int k0 = ks * 64;
#pragma unroll
        for (int q = 0; q < 4; ++q) {
            const int c = q * 4 + wid, row = c * 8 + srow;
            gload_lds16(A + (size_t)(row0 + row) * K + k0 + ssw * 8, ldsA + c * 512);
        }
#pragma unroll
        for (int q = 0; q < 4; ++q) {
            const int c = q * 4 + wid, row = c * 8 + srow;
            gload_lds16(B + (size_t)(col0 + row) * K + k0 + ssw * 8, ldsB + c * 512);
        }
        __syncthreads();
        const bf16x8* A8 = (const bf16x8*)ldsA;
        const bf16x8* B8 = (const bf16x8*)ldsB;
        bf16x8 af[4][2], bfr[4][2];
#pragma unroll
        for (int m = 0; m < 4; ++m) {
            const int ar = wr * 64 + m * 16 + (lane & 15);
#pragma unroll
            for (int ks2 = 0; ks2 < 2; ++ks2)
                af[m][ks2] = A8[ar * 8 + ((ks2 * 4 + (lane >> 4)) ^ (ar & 7))];
        }
#pragma unroll
        for (int n = 0; n < 4; ++n) {
            const int br = wc * 64 + n * 16 + (lane & 15);
#pragma unroll
            for (int ks2 = 0; ks2 < 2; ++ks2)
                bfr[n][ks2] = B8[br * 8 + ((ks2 * 4 + (lane >> 4)) ^ (br & 7))];
        }
#pragma unroll
        for (int ks2 = 0; ks2 < 2; ++ks2)
#pragma unroll
            for (int m = 0; m < 4; ++m)
#pragma unroll
                for (int n = 0; n < 4; ++n)
                    acc[m][n] = __builtin_amdgcn_mfma_f32_16x16x32_bf16(
                        af[m][ks2], bfr[n][ks2], acc[m][n], 0, 0, 0);
        __syncthreads();
    }
#pragma unroll
    for (int m = 0; m < 4; ++m)
#pragma unroll
        for (int n = 0; n < 4; ++n) {
            const int col = col0 + wc * 64 + n * 16 + (lane & 15);
            if (col < PCAT) {
#pragma unroll
                for (int r = 0; r < 4; ++r) {
                    const int row = row0 + wr * 64 + m * 16 + (lane >> 4) * 4 + r;
                    HB[(size_t)row * PCAT + col] = f32_to_bf16(acc[m][n][r]);
                }
            }
        }
}

// ---------------- mega kernel sections ----------------
// head section (tile 128x128, K=1024) — per-(col-tile, wc-half) partial store.
// Target lookups happen in the EPILOGUE (not carried across the K-loop; r13's
// prologue-load + forced 5-wave bound spilled: VGPR 64->48, 68 MB scratch).
static __device__ void head_section(int rb, int ct,
                                    const u16* __restrict__ A, const u16* __restrict__ B,
                                    const int* __restrict__ tgt,
                                    float* __restrict__ SEHp, float* __restrict__ TL,
                                    u16* ldsA, u16* ldsB)
{
    constexpr int K = INF;
    const int tid = threadIdx.x, wid = tid >> 6, lane = tid & 63;
    const int wr = wid >> 1, wc = wid & 1;
    const int row0 = rb * 128, col0 = ct * 128;

    f32x4 acc[4][4];
#pragma unroll
    for (int m = 0; m < 4; ++m)
#pragma unroll
        for (int n = 0; n < 4; ++n) acc[m][n] = (f32x4){0.f, 0.f, 0.f, 0.f};

    const int srow = lane >> 3;
    const int ssw  = (lane & 7) ^ srow;

    for (int ks = 0; ks < K / 64; ++ks) {
        const int k0 = ks * 64;
#pragma unroll
        for (int q = 0; q < 4; ++q) {
            const int c = q * 4 + wid, row = c * 8 + srow;
            gload_lds16(A + (size_t)(row0 + row) * K + k0 + ssw * 8, ldsA + c * 512);
        }
#pragma unroll
        for (int q = 0; q < 4; ++q) {
            const int c = q * 4 + wid, row = c * 8 + srow;
            gload_lds16(B + (size_t)(col0 + row) * K + k0 + ssw * 8, ldsB + c * 512);
        }
        __syncthreads();
        const bf16x8* A8 = (const bf16x8*)ldsA;
        const bf16x8* B8 = (const bf16x8*)ldsB;
        bf16x8 af[4][2], bfr[4][2];
#pragma unroll
        for (int m = 0; m < 4; ++m) {
            const int ar = wr * 64 + m * 16 + (lane & 15);
#pragma unroll
            for (int ks2 = 0; ks2 < 2; ++ks2)
                af[m][ks2] = A8[ar * 8 + ((ks2 * 4 + (lane >> 4)) ^ (ar & 7))];
        }
#pragma unroll
        for (int n = 0; n < 4; ++n) {
            const int br = wc * 64 + n * 16 + (lane & 15);
#pragma unroll
            for (int ks2 = 0; ks2 < 2; ++ks2)
                bfr[n][ks2] = B8[br * 8 + ((ks2 * 4 + (lane >> 4)) ^ (br & 7))];
        }
#pragma unroll
        for (int ks2 = 0; ks2 < 2; ++ks2)
#pragma unroll
            for (int m = 0; m < 4; ++m)
#pragma unroll
                for (int n = 0; n < 4; ++n)
                    acc[m][n] = __builtin_amdgcn_mfma_f32_16x16x32_bf16(
                        af[m][ks2], bfr[n][ks2], acc[m][n], 0, 0, 0);
        __syncthreads();
    }

    const int slot = ct * 2 + wc;
#pragma unroll
    for (int m = 0; m < 4; ++m) {
        // target headclass for the 4 rows this m-iteration covers (epilogue-local)
        int th[4];
#pragma unroll
        for (int r = 0; r < 4; ++r) {
            const int t = tgt[row0 + wr * 64 + m * 16 + (lane >> 4) * 4 + r];
            th[r] = (t < 0) ? 0 : (t < C0_LO ? t : (t < C0_HI ? C0_LO : C0_LO + 1));
        }
        f32x4 rs = (f32x4){0.f, 0.f, 0.f, 0.f};
#pragma unroll
        for (int n = 0; n < 4; ++n) {
            const int cls = col0 + wc * 64 + n * 16 + (lane & 15);
            if (cls < HEAD_N) {
#pragma unroll
                for (int r = 0; r < 4; ++r) {
                    rs[r] += fast_exp2(acc[m][n][r]);
                    if (th[r] == cls) {
                        const int lrow = wr * 64 + m * 16 + (lane >> 4) * 4 + r;
                        TL[row0 + lrow] = acc[m][n][r];
                    }
                }
            }
        }
#pragma unroll
        for (int msk = 1; msk < 16; msk <<= 1)
#pragma unroll
            for (int r = 0; r < 4; ++r) rs[r] += __shfl_xor(rs[r], msk, 64);
        if ((lane & 15) == 0) {
            const int rbase = row0 + wr * 64 + m * 16 + (lane >> 4) * 4;
#pragma unroll
            for (int r = 0; r < 4; ++r) SEHp[(size_t)slot * NR + rbase + r] = rs[r];
        }
    }
}

// cluster section: compacted rows in registers, W streamed via double-buffered LDS
template<int K, int CT, int MSETS>
static __device__ void sumexp_section(const u16* __restrict__ Hbase, int ldh,
                                      const int* __restrict__ list,
                                      const u16* __restrict__ W,
                                      int nreal, int ntiles, int tps,
                                      int rb, int split, float* __restrict__ SEp,
                                      u16* lds)
{
    constexpr int NKF   = K / 32;
    constexpr int SLOTS = K / 8;
    constexpr int CHUNKS = CT * K * 2 / 4096;
    constexpr int RPC   = 256 / SLOTS;
    constexpr int NT    = CT / 16;
    constexpr int BROWS = MSETS * 64;       // rows per block

    const int tid = threadIdx.x, wid = tid >> 6, lane = tid & 63;
    const int row0 = rb * BROWS + wid * (MSETS * 16);

    const int t0 = split * tps;
    const int t1 = min(t0 + tps, ntiles);

    bf16x8 afr[MSETS][NKF];
#pragma unroll
    for (int m = 0; m < MSETS; ++m) {
        const int orow = list[row0 + m * 16 + (lane & 15)];
        const u16* hr = Hbase + (size_t)orow * ldh + (lane >> 4) * 8;
#pragma unroll
        for (int kf = 0; kf < NKF; ++kf)
            afr[m][kf] = *(const bf16x8*)(hr + kf * 32);
    }

    float rs[MSETS][4];
#pragma unroll
    for (int m = 0; m < MSETS; ++m)
#pragma unroll
        for (int r = 0; r < 4; ++r) rs[m][r] = 0.f;

    const int trow  = tid / SLOTS;
    const int swoff = ((tid % SLOTS) ^ (trow & 7)) * 8;

    auto STAGE = [&](int t, int buf) {
        const u16* wb = W + (size_t)t * CT * K + (size_t)trow * K + swoff;
        u16* lb = lds + buf * (CT * K) + wid * 512;
#pragma unroll
        for (int c = 0; c < CHUNKS; ++c)
            gload_lds16(wb + (size_t)c * RPC * K, lb + c * 2048);
    };

    int cur = 0;
    STAGE(t0, 0);
    __syncthreads();

    for (int t = t0; t < t1; ++t) {
        if (t + 1 < t1) STAGE(t + 1, cur ^ 1);
        const bf16x8* B8 = (const bf16x8*)(lds + cur * (CT * K));
        const bool full = (t + 1) * CT <= nreal;
#pragma unroll
        for (int n = 0; n < NT; ++n) {
            const int br = n * 16 + (lane & 15);
            bf16x8 bfr[NKF];
#pragma unroll
            for (int kf = 0; kf < NKF; ++kf)
                bfr[kf] = B8[br * SLOTS + ((kf * 4 + (lane >> 4)) ^ (br & 7))];
            f32x4 acc[MSETS];
#pragma unroll
            for (int m = 0; m < MSETS; ++m) acc[m] = (f32x4){0.f, 0.f, 0.f, 0.f};
#pragma unroll
            for (int m = 0; m < MSETS; ++m)
#pragma unroll
                for (int kf = 0; kf < NKF; ++kf)
                    acc[m] = __builtin_amdgcn_mfma_f32_16x16x32_bf16(
                        afr[m][kf], bfr[kf], acc[m], 0, 0, 0);
            if (full || (t * CT + n * 16 + (lane & 15)) < nreal) {
#pragma unroll
                for (int m = 0; m < MSETS; ++m)
#pragma unroll
                    for (int r = 0; r < 4; ++r) rs[m][r] += fast_exp2(acc[m][r]);
            }
        }
        __syncthreads();
        cur ^= 1;
    }

#pragma unroll
    for (int msk = 1; msk < 16; msk <<= 1)
#pragma unroll
        for (int m = 0; m < MSETS; ++m)
#pragma unroll
            for (int r = 0; r < 4; ++r) rs[m][r] += __shfl_xor(rs[m][r], msk, 64);
    if ((lane & 15) == 0) {
        const int rbase = row0 + (lane >> 4) * 4;
#pragma unroll
        for (int m = 0; m < MSETS; ++m)
#pragma unroll
            for (int r = 0; r < 4; ++r)
                SEp[(size_t)split * NR + rbase + m * 16 + r] = rs[m][r];
    }
}

// Type-sequential layout + ghost-free grid-stride. LDS = 32 KB exactly; with
// natural ~64 VGPR the HW fits 5 blocks/CU (bounds kept at 4 so the allocator
// is NOT squeezed — r13's forced (256,5) caused 68 MB of scratch spill).
__launch_bounds__(256, 4)
__global__ void mega_kernel(const u16* __restrict__ xb, const u16* __restrict__ whb,
                            const u16* __restrict__ hcatb,
                            const u16* __restrict__ o0b, const u16* __restrict__ o1b,
                            const int* __restrict__ tgt,
                            const int* __restrict__ c0list, const int* __restrict__ c1list,
                            const int* __restrict__ cnts,
                            float* __restrict__ SEHp, float* __restrict__ TL,
                            float* __restrict__ C0p, float* __restrict__ C1p)
{
    __shared__ u16 smem[2][8192];
    const int bid = blockIdx.x;

    if (bid < HEADB) {
        head_section(bid & 31, bid >> 5, xb, whb, tgt, SEHp, TL,
                     smem[0], smem[1]);
    } else if (bid < HEADB + C1SLOTS) {
        const int c = bid - HEADB;
        const int W1 = (cnts[3] >> 8) * S1;     // live 256-row groups * splits
        for (int w = c; w < W1; w += C1SLOTS)
            sumexp_section<K1, 128, 4>(hcatb + 256, PCAT, c1list, o1b,
                                       C1_N, C1_NP / 128, TPS1, w / S1, w % S1, C1p, smem[0]);
    } else {
        const int c = bid - (HEADB + C1SLOTS);
        const int W0 = (cnts[2] >> 7) * S0;     // live 128-row groups * splits
        for (int w = c; w < W0; w += C0SLOTS)
            sumexp_section<K0, 32, 2>(hcatb, PCAT, c0list, o0b,
                                      C0_N, C0_N / 32, TPS0, w / S0, w % S0, C0p, smem[0]);
    }
}

// ---------------- per-row epilogue: one wave per row (contention-free stores) ----------------
__global__ void epilogue_kernel(const int* __restrict__ tgt, const float* __restrict__ tl,
                                const float* __restrict__ out0, const float* __restrict__ out1,
                                const u16* __restrict__ hcatb,
                                const float* __restrict__ SEHp, const float* __restrict__ C0p,
                                const float* __restrict__ C1p, const int* __restrict__ crow,
                                float* __restrict__ rowlogp, float* __restrict__ rowvalid) {
    const int wid = threadIdx.x >> 6, lane = threadIdx.x & 63;
    const int r = blockIdx.x * 4 + wid;
    const int t = tgt[r];
    const bool valid = (t != IGNORE);
    const int tc = valid ? t : 0;
    const int band = (tc < C0_LO) ? 0 : (tc < C0_HI) ? 1 : 2;
    const int cr = crow[r];

    float p2 = 0.f;
    if (band == 1) {
        const u16* hr = hcatb + (size_t)r * PCAT;
        const float* crp = out0 + (size_t)(tc - C0_LO) * K0;
        for (int k = lane; k < K0; k += 64) p2 += bf2f(hr[k]) * crp[k];
    } else if (band == 2) {
        p2 = bf2f(hcatb[(size_t)r * PCAT + 256 + lane]) * out1[(size_t)(tc - C0_HI) * K1 + lane];
    }
#pragma unroll
    for (int msk = 32; msk >= 1; msk >>= 1) p2 += __shfl_xor(p2, msk, 64);

    float hp = (lane < NHP) ? SEHp[(size_t)lane * NR + r] : 0.f;
    float cp = 0.f;
    if (band == 1 && lane < S0) cp = C0p[(size_t)lane * NR + cr];
    if (band == 2 && lane < S1) cp = C1p[(size_t)lane * NR + cr];
#pragma unroll
    for (int msk = 1; msk < 64; msk <<= 1) {
        hp += __shfl_xor(hp, msk, 64);
        cp += __shfl_xor(cp, msk, 64);
    }

    if (lane == 0) {
        float logp = LN2 * tl[r] - __logf(hp);
        if (band != 0) logp += p2 - __logf(cp);
        rowlogp[r]  = valid ? logp : 0.f;
        rowvalid[r] = valid ? 1.f : 0.f;
    }
}

// ---------------- deterministic final reduce ----------------
__global__ void final_reduce(const float* __restrict__ rowlogp,
                             const float* __restrict__ rowvalid, float* __restrict__ out) {
    __shared__ float sl[256], sv[256];
    const int tid = threadIdx.x;
    float a = 0.f, b = 0.f;
    for (int i = tid; i < NR; i += 256) { a += rowlogp[i]; b += rowvalid[i]; }
    sl[tid] = a; sv[tid] = b;
    __syncthreads();
    for (int s = 128; s > 0; s >>= 1) {
        if (tid < s) { sl[tid] += sl[tid + s]; sv[tid] += sv[tid + s]; }
        __syncthreads();
    }
    if (tid == 0) out[0] = -sl[0] / sv[0];
}

extern "C" void kernel_launch(void* const* d_in, const int* in_sizes, int n_in,
                              void* d_out, int out_size, void* d_ws, size_t ws_size,
                              hipStream_t stream) {
    const float* x      = (const float*)d_in[0];
    const int*   tgt    = (const int*)d_in[1];
    const float* head_w = (const float*)d_in[2];
    const float* proj0  = (const float*)d_in[3];
    const float* out0   = (const float*)d_in[4];
    const float* proj1  = (const float*)d_in[5];
    const float* out1   = (const float*)d_in[6];
    float* loss = (float*)d_out;

    char* base = (char*)d_ws;
    size_t off = 0;
    auto alloc = [&](size_t bytes) { char* p = base + off; off += (bytes + 255) & ~(size_t)255; return p; };

    u16* xb    = (u16*)alloc((size_t)NR * INF * 2);
    u16* wcatb = (u16*)alloc((size_t)WCAT_R * INF * 2);
    u16* o0b   = (u16*)alloc((size_t)C0_N * K0 * 2);
    u16* o1b   = (u16*)alloc((size_t)C1_NP * K1 * 2);
    u16* hcatb = (u16*)alloc((size_t)NR * PCAT * 2);
    float* SEHp = (float*)alloc((size_t)NHP * NR * 4);
    float* C0p  = (float*)alloc((size_t)S0 * NR * 4);
    float* C1p  = (float*)alloc((size_t)S1 * NR * 4);
    float* tl   = (float*)alloc((size_t)NR * 4);
    int* c0list = (int*)alloc((size_t)(NR + 256) * 4);
    int* c1list = (int*)alloc((size_t)(NR + 256) * 4);
    int* crow   = (int*)alloc((size_t)NR * 4);
    int* cnts   = (int*)alloc(4 * 4);
    float* rowlogp  = (float*)alloc((size_t)NR * 4);
    float* rowvalid = (float*)alloc((size_t)NR * 4);

    CvtSegs segs;
    segs.s[0] = x;      segs.d[0] = xb;                              segs.n8[0] = NR * INF / 8;      segs.sc[0] = 1.0f;
    segs.s[1] = head_w; segs.d[1] = wcatb;                           segs.n8[1] = HEAD_N * INF / 8;  segs.sc[1] = LOG2E;
    segs.s[2] = proj0;  segs.d[2] = wcatb + (size_t)HEAD_NP * INF;   segs.n8[2] = 256 * INF / 8;     segs.sc[2] = 1.0f;
    segs.s[3] = proj1;  segs.d[3] = wcatb + (size_t)(HEAD_NP + 256) * INF; segs.n8[3] = 64 * INF / 8; segs.sc[3] = 1.0f;
    segs.s[4] = out0;   segs.d[4] = o0b;                             segs.n8[4] = C0_N * K0 / 8;     segs.sc[4] = LOG2E;
    segs.s[5] = out1;   segs.d[5] = o1b;                             segs.n8[5] = C1_N * K1 / 8;     segs.sc[5] = LOG2E;
    cvt_compact<<<2048, 256, 0, stream>>>(segs, tgt, c0list, c1list, crow, cnts);

    // hcat = X @ [proj0;proj1]^T  (bf16; LDS-staged tile GEMM)
    proj_tile<<<dim3(32, PCAT_P / 128), 256, 0, stream>>>(xb, wcatb + (size_t)HEAD_NP * INF, hcatb);

    // head GEMM+sumexp, then C1 (256-row blocks), then C0 (type-sequential, ghost-free)
    mega_kernel<<<MEGA_GRID, 256, 0, stream>>>(xb, wcatb, hcatb, o0b, o1b, tgt,
                                               c0list, c1list, cnts, SEHp, tl, C0p, C1p);

    epilogue_kernel<<<NR / 4, 256, 0, stream>>>(tgt, tl, out0, out1, hcatb,
                                                SEHp, C0p, C1p, crow, rowlogp, rowvalid);
    final_reduce<<<1, 256, 0, stream>>>(rowlogp, rowvalid, loss);
    (void)in_sizes; (void)n_in; (void)out_size; (void)ws_size;
}